// Round 11
// baseline (180.104 us; speedup 1.0000x reference)
//
#include <hip/hip_runtime.h>
#include <math.h>

// Problem constants
#define SS 64
#define EE 512
#define L2T 13.544f
#define LNEPS 1e-5f

using bf16x8 = __attribute__((ext_vector_type(8))) __bf16;
using u16x8  = __attribute__((ext_vector_type(8))) unsigned short;
using f32x4  = __attribute__((ext_vector_type(4))) float;

typedef const void __attribute__((address_space(1))) cv_global;
typedef void __attribute__((address_space(3))) v_lds;

__device__ inline unsigned short f2bf(float f) {
    union { float f; unsigned u; } v; v.f = f;
    unsigned r = v.u + 0x7fff + ((v.u >> 16) & 1);
    return (unsigned short)(r >> 16);
}
__device__ inline float bf2f(unsigned short h) {
    union { unsigned u; float f; } v; v.u = (unsigned)h << 16;
    return v.f;
}

#define MFMA16 __builtin_amdgcn_mfma_f32_16x16x32_bf16

// bb (ushort offsets):
#define XB_O    0
#define WFULL_O 1048576
#define W1CB_O  1966080
#define W2B_O   2490368
#define QKVB_O  2752512
#define X1O_O   5898240
#define HB_O    7995392
#define PB_O    9043968

// ---------------------------------------------------------------------------
// MEGA-1: weight convert (0-1407) + Wc=W1b@Wo prep (1408-1471) + b_eff
// (1472-1475) + Gram-based L2 attention (1476-1539; 2 blocks/batch).
// ---------------------------------------------------------------------------
__global__ __launch_bounds__(256)
void mega1(const float* __restrict__ x, const float* __restrict__ Wqkv,
           const float* __restrict__ Wo, const float* __restrict__ W1,
           const float* __restrict__ W2, const float* __restrict__ d1,
           const float* __restrict__ d2, const float* __restrict__ b1,
           const float* __restrict__ bo, unsigned short* __restrict__ bb,
           float* __restrict__ b_eff, float* __restrict__ x1_attn,
           unsigned short* __restrict__ Pl2) {
    const int bx = blockIdx.x, tid = threadIdx.x;
    __shared__ __align__(16) char smem[36096];

    if (bx < 1408) {
        int i = bx * 256 + tid;
        ushort4* dst4 = (ushort4*)bb;
        const float4* s; int di;
        if (i < 196608)      { s = (const float4*)Wqkv + i;          di = WFULL_O/4 + i; }
        else if (i < 212992) { int j = i-196608; s = (const float4*)d1 + j; di = WFULL_O/4 + 196608 + j; }
        else if (i < 229376) { int j = i-212992; s = (const float4*)d2 + j; di = WFULL_O/4 + 212992 + j; }
        else if (i < 294912) { int j = i-229376; s = (const float4*)W2 + j; di = W2B_O/4 + j; }
        else                 { int j = i-294912; int r = j>>7, cq = j&127;
                               s = (const float4*)W1 + r*256 + cq;   di = W1CB_O/4 + r*256 + cq; }
        float4 v = *s;
        ushort4 o;
        o.x = f2bf(v.x); o.y = f2bf(v.y); o.z = f2bf(v.z); o.w = f2bf(v.w);
        dst4[di] = o;
    } else if (bx < 1472) {
        const int tb = bx - 1408;
        const int m0 = (tb >> 3) * 64, n0 = (tb & 7) * 64;
        unsigned short* Asl = (unsigned short*)smem;   // [64][40]
        unsigned short* Bsl = Asl + 64 * 40;           // [64][40]
        const int wave = tid >> 6, lane = tid & 63;
        const int wm = (wave >> 1) * 32, wn = (wave & 1) * 32;
        const int fr = lane & 15, kq = (lane >> 4) * 8;
        f32x4 acc[2][2] = {};
        for (int k0 = 0; k0 < 512; k0 += 32) {
            {
                int m = tid >> 2, kk = (tid & 3) * 8;
                const float* src = W1 + (size_t)(m0 + m) * 1024 + 512 + k0 + kk;
                float4 v0 = *(const float4*)src, v1 = *(const float4*)(src + 4);
                u16x8 t = {f2bf(v0.x), f2bf(v0.y), f2bf(v0.z), f2bf(v0.w),
                           f2bf(v1.x), f2bf(v1.y), f2bf(v1.z), f2bf(v1.w)};
                *(u16x8*)(Asl + m * 40 + kk) = t;
            }
            {
                int k = tid >> 3, jq = (tid & 7) * 8;
                const float* src = Wo + (size_t)(k0 + k) * 512 + n0 + jq;
                float4 v0 = *(const float4*)src, v1 = *(const float4*)(src + 4);
                float vv[8] = {v0.x, v0.y, v0.z, v0.w, v1.x, v1.y, v1.z, v1.w};
                #pragma unroll
                for (int e = 0; e < 8; ++e) Bsl[(jq + e) * 40 + k] = f2bf(vv[e]);
            }
            __syncthreads();
            bf16x8 a0 = *(const bf16x8*)(Asl + (wm + fr) * 40 + kq);
            bf16x8 a1 = *(const bf16x8*)(Asl + (wm + 16 + fr) * 40 + kq);
            bf16x8 b0 = *(const bf16x8*)(Bsl + (wn + fr) * 40 + kq);
            bf16x8 b1 = *(const bf16x8*)(Bsl + (wn + 16 + fr) * 40 + kq);
            acc[0][0] = MFMA16(a0, b0, acc[0][0], 0, 0, 0);
            acc[0][1] = MFMA16(a0, b1, acc[0][1], 0, 0, 0);
            acc[1][0] = MFMA16(a1, b0, acc[1][0], 0, 0, 0);
            acc[1][1] = MFMA16(a1, b1, acc[1][1], 0, 0, 0);
            __syncthreads();
        }
        unsigned short* W1cb = bb + W1CB_O;
        const int crow = (lane >> 4) * 4, ccol = lane & 15;
        #pragma unroll
        for (int r2 = 0; r2 < 2; ++r2)
            #pragma unroll
            for (int c2 = 0; c2 < 2; ++c2)
                #pragma unroll
                for (int i = 0; i < 4; ++i) {
                    int m = m0 + wm + r2 * 16 + crow + i;
                    int j = n0 + wn + c2 * 16 + ccol;
                    W1cb[(size_t)m * 1024 + 512 + j] = f2bf(acc[r2][c2][i]);
                }
    } else if (bx < 1476) {
        int n = (bx - 1472) * 128 + (tid >> 1);
        int kh = (tid & 1) * 256;
        float s = 0.f;
        for (int k = 0; k < 256; ++k)
            s += W1[(size_t)n * 1024 + 512 + kh + k] * bo[kh + k];
        s += __shfl_xor(s, 1);
        if ((tid & 1) == 0) b_eff[n] = b1[n] + s;
    } else {
        // Gram-based L2 attention (bf16x3 split), 2 blocks/batch (32 rows ea).
        const int idx = bx - 1476;
        const int b = idx >> 1, hf = idx & 1;
        unsigned short* Xhi = (unsigned short*)smem;   // [64][72]
        unsigned short* Xlo = Xhi + 64 * 72;           // [64][72]
        float* sc    = (float*)(smem + 18432);         // [32][68]
        float* norms = (float*)(smem + 27136);         // [64] (fp32 exact)
        const int wave = tid >> 6, lane = tid & 63;
        const int fr = lane & 15;
        const int srow = tid >> 2, scq = (tid & 3) * 16;
        const int wmg = hf * 32 + (wave >> 1) * 16;
        const int wn = (wave & 1) * 32;

        f32x4 acc[2] = {};
        float nsq = 0.f;
        const float* xrow = x + (size_t)b * 32768;
        unsigned short* xbg = bb + XB_O + (size_t)b * 32768;

        for (int k0 = 0; k0 < 512; k0 += 64) {
            const float* src = xrow + srow * 512 + k0 + scq;
            u16x8 hi0, hi1, lo0, lo1;
            #pragma unroll
            for (int e = 0; e < 8; ++e) {
                float v = src[e];
                nsq += v * v;
                unsigned short h = f2bf(v);
                hi0[e] = h; lo0[e] = f2bf(v - bf2f(h));
            }
            #pragma unroll
            for (int e = 0; e < 8; ++e) {
                float v = src[8 + e];
                nsq += v * v;
                unsigned short h = f2bf(v);
                hi1[e] = h; lo1[e] = f2bf(v - bf2f(h));
            }
            *(u16x8*)(Xhi + srow * 72 + scq)     = hi0;
            *(u16x8*)(Xhi + srow * 72 + scq + 8) = hi1;
            *(u16x8*)(Xlo + srow * 72 + scq)     = lo0;
            *(u16x8*)(Xlo + srow * 72 + scq + 8) = lo1;
            if (hf == 0) {
                *(u16x8*)(xbg + srow * 512 + k0 + scq)     = hi0;
                *(u16x8*)(xbg + srow * 512 + k0 + scq + 8) = hi1;
            }
            __syncthreads();
            #pragma unroll
            for (int j = 0; j < 2; ++j) {
                int kk = j * 32 + (lane >> 4) * 8;
                bf16x8 ah = *(const bf16x8*)(Xhi + (wmg + fr) * 72 + kk);
                bf16x8 al = *(const bf16x8*)(Xlo + (wmg + fr) * 72 + kk);
                #pragma unroll
                for (int c2 = 0; c2 < 2; ++c2) {
                    bf16x8 bh = *(const bf16x8*)(Xhi + (wn + c2 * 16 + fr) * 72 + kk);
                    bf16x8 bl = *(const bf16x8*)(Xlo + (wn + c2 * 16 + fr) * 72 + kk);
                    acc[c2] = MFMA16(ah, bh, acc[c2], 0, 0, 0);
                    acc[c2] = MFMA16(ah, bl, acc[c2], 0, 0, 0);
                    acc[c2] = MFMA16(al, bh, acc[c2], 0, 0, 0);
                }
            }
            __syncthreads();
        }
        nsq += __shfl_xor(nsq, 1);
        nsq += __shfl_xor(nsq, 2);
        if ((tid & 3) == 0) norms[srow] = nsq;
        const int crow = (lane >> 4) * 4, ccol = lane & 15;
        #pragma unroll
        for (int c2 = 0; c2 < 2; ++c2)
            #pragma unroll
            for (int i = 0; i < 4; ++i)
                sc[(wmg - hf * 32 + crow + i) * 68 + wn + c2 * 16 + ccol] =
                    acc[c2][i];
        __syncthreads();
        #pragma unroll
        for (int i = 0; i < 8; ++i) {
            int lr = wave * 8 + i;
            int f = hf * 32 + lr;
            float nf = norms[f];
            float val = (2.f * sc[lr * 68 + lane] - nf - norms[lane]) * (1.0f / L2T);
            float mx = val;
            #pragma unroll
            for (int m = 32; m; m >>= 1) mx = fmaxf(mx, __shfl_xor(mx, m));
            float e = expf(val - mx);
            float sum = e;
            #pragma unroll
            for (int m = 32; m; m >>= 1) sum += __shfl_xor(sum, m);
            float a = e / sum;
            x1_attn[((size_t)b * 64 + f) * 64 + lane] = a;
            Pl2[((size_t)b * 64 + f) * 64 + lane] = f2bf(a);
        }
    }
}

// ---------------------------------------------------------------------------
// Fused qkv + P GEMM + x1-apply.  Wfull = [Wqkv(1536) ; d1W1 ; d2W1].
// bx<24 -> qkvb; 24<=bx<28 -> Pb; bx>=28 -> x1 = Pl2 @ xb (per (b, e-tile)).
// ---------------------------------------------------------------------------
__global__ __launch_bounds__(256)
void gemm_qkvp(const unsigned short* __restrict__ A,
               const unsigned short* __restrict__ B,
               const float* __restrict__ bias,
               unsigned short* __restrict__ Cq, unsigned short* __restrict__ Cp,
               const unsigned short* __restrict__ Pl2,
               unsigned short* __restrict__ x1o) {
    __shared__ unsigned short qsm[8704];
    const int tid = threadIdx.x, wave = tid >> 6, lane = tid & 63;
    const int fr = lane & 15;
    const int crow = (lane >> 4) * 4, ccol = lane & 15;

    if (blockIdx.x < 28) {
        unsigned short* Asl = qsm;
        unsigned short* Bsl = qsm + 4096;
        const int m0 = blockIdx.y * 64, n0 = blockIdx.x * 64;
        const int wm = (wave >> 1) * 32, wn = (wave & 1) * 32;
        f32x4 acc[2][2] = {};

        for (int k0 = 0; k0 < 512; k0 += 64) {
            #pragma unroll
            for (int c0 = 0; c0 < 512; c0 += 256) {
                int cc = c0 + tid, r = cc >> 3, q = cc & 7;
                int col = (q ^ (r & 7)) * 8;
                __builtin_amdgcn_global_load_lds(
                    (cv_global*)(A + (size_t)(m0 + r) * 512 + k0 + col),
                    (v_lds*)(Asl + c0 * 8 + wave * 512), 16, 0, 0);
            }
            #pragma unroll
            for (int c0 = 0; c0 < 512; c0 += 256) {
                int cc = c0 + tid, r = cc >> 3, q = cc & 7;
                int col = (q ^ (r & 7)) * 8;
                __builtin_amdgcn_global_load_lds(
                    (cv_global*)(B + (size_t)(n0 + r) * 512 + k0 + col),
                    (v_lds*)(Bsl + c0 * 8 + wave * 512), 16, 0, 0);
            }
            __syncthreads();
            #pragma unroll
            for (int j = 0; j < 2; ++j) {
                int kc = (lane >> 4) + j * 4;
                int rb0 = wn + fr, rb1 = wn + 16 + fr;
                bf16x8 b0 = *(const bf16x8*)(Bsl + rb0 * 64 + (kc ^ (rb0 & 7)) * 8);
                bf16x8 b1 = *(const bf16x8*)(Bsl + rb1 * 64 + (kc ^ (rb1 & 7)) * 8);
                #pragma unroll
                for (int r = 0; r < 2; ++r) {
                    int ra = wm + r * 16 + fr;
                    bf16x8 af = *(const bf16x8*)(Asl + ra * 64 + (kc ^ (ra & 7)) * 8);
                    acc[r][0] = MFMA16(af, b0, acc[r][0], 0, 0, 0);
                    acc[r][1] = MFMA16(af, b1, acc[r][1], 0, 0, 0);
                }
            }
            __syncthreads();
        }

        if (blockIdx.x < 24) {
            float bj0 = bias[n0 + wn + ccol], bj1 = bias[n0 + wn + 16 + ccol];
            #pragma unroll
            for (int r = 0; r < 2; ++r)
                #pragma unroll
                for (int c = 0; c < 2; ++c) {
                    float bj = c ? bj1 : bj0;
                    #pragma unroll
                    for (int i = 0; i < 4; ++i) {
                        size_t m = (size_t)(m0 + wm + r * 16 + crow + i);
                        int n = n0 + wn + c * 16 + ccol;
                        Cq[m * 1536 + n] = f2bf(acc[r][c][i] + bj);
                    }
                }
        } else {
            int p0 = n0 - 1536;
            #pragma unroll
            for (int r = 0; r < 2; ++r)
                #pragma unroll
                for (int c = 0; c < 2; ++c)
                    #pragma unroll
                    for (int i = 0; i < 4; ++i) {
                        size_t m = (size_t)(m0 + wm + r * 16 + crow + i);
                        int n = p0 + wn + c * 16 + ccol;
                        Cp[m * 256 + n] = f2bf(acc[r][c][i]);
                    }
        }
    } else {
        // x1[b, :, e0:e0+64] = Pl2 @ xb
        const int e0 = (blockIdx.x - 28) * 64;
        const int b = blockIdx.y;
        unsigned short* Ap = qsm;            // [64][68]
        unsigned short* Xt = qsm + 64 * 68;  // [64][68]
        {
            int row = tid >> 2, cq2 = (tid & 3) * 16;
            const unsigned short* src = Pl2 + (size_t)b * 4096 + row * 64 + cq2;
            *(u16x8*)(Ap + row * 68 + cq2)     = *(const u16x8*)src;
            *(u16x8*)(Ap + row * 68 + cq2 + 8) = *(const u16x8*)(src + 8);
        }
        {
            int g = tid >> 2, cq2 = (tid & 3) * 16;
            const unsigned short* src = A + (size_t)b * 32768 + g * 512 + e0 + cq2;
            u16x8 v0 = *(const u16x8*)src, v1 = *(const u16x8*)(src + 8);
            #pragma unroll
            for (int e = 0; e < 8; ++e) Xt[(cq2 + e) * 68 + g] = v0[e];
            #pragma unroll
            for (int e = 0; e < 8; ++e) Xt[(cq2 + 8 + e) * 68 + g] = v1[e];
        }
        __syncthreads();
        const int wm2 = wave * 16, kq = (lane >> 4) * 8;
        f32x4 o[4] = {};
        #pragma unroll
        for (int j = 0; j < 2; ++j) {
            int kk = j * 32 + kq;
            bf16x8 a = *(const bf16x8*)(Ap + (wm2 + fr) * 68 + kk);
            #pragma unroll
            for (int t = 0; t < 4; ++t) {
                bf16x8 bv = *(const bf16x8*)(Xt + (t * 16 + fr) * 68 + kk);
                o[t] = MFMA16(a, bv, o[t], 0, 0, 0);
            }
        }
        #pragma unroll
        for (int t = 0; t < 4; ++t)
            #pragma unroll
            for (int i = 0; i < 4; ++i) {
                size_t m = (size_t)b * 64 + wm2 + crow + i;
                x1o[m * 1024 + e0 + t * 16 + ccol] = f2bf(o[t][i]);
            }
    }
}

// ---------------------------------------------------------------------------
// MFMA attention. Block per (b, h, half). Q read direct from global (L2-hot,
// per-lane 16B — verified correct in R8). o -> x1o[:,512:].
// ---------------------------------------------------------------------------
__global__ __launch_bounds__(256)
void mha_attn(const unsigned short* __restrict__ qkv,
              unsigned short* __restrict__ x1o, float* __restrict__ pws) {
    const int hh = blockIdx.x;
    const int h = hh >> 1, half = hh & 1;
    const int b = blockIdx.y;
    const int tid = threadIdx.x, wave = tid >> 6, lane = tid & 63;

    __shared__ unsigned short Ks[64 * 136];
    __shared__ unsigned short Vt[128 * 72];
    __shared__ float sc[32 * 68];
    __shared__ unsigned short Pbf[32 * 72];

    const unsigned short* base = qkv + (size_t)b * 64 * 1536;
    {
        int row = tid >> 2, col = (tid & 3) * 32;
        const unsigned short* src = base + row * 1536 + 512 + h * 128 + col;
        #pragma unroll
        for (int j = 0; j < 4; ++j)
            *(u16x8*)(Ks + row * 136 + col + j * 8) = *(const u16x8*)(src + j * 8);
    }
    {
        int g = tid >> 2, col = (tid & 3) * 32;
        const unsigned short* src = base + g * 1536 + 1024 + h * 128 + col;
        #pragma unroll
        for (int j = 0; j < 4; ++j) {
            u16x8 v = *(const u16x8*)(src + j * 8);
            #pragma unroll
            for (int e = 0; e < 8; ++e)
                Vt[(col + j * 8 + e) * 72 + g] = v[e];
        }
    }
    __syncthreads();

    const int fr = lane & 15, kq = (lane >> 4) * 8;
    const int crow = (lane >> 4) * 4, ccol = lane & 15;
    const int wm = (wave >> 1) * 16;
    {
        const int wn = (wave & 1) * 32;
        const unsigned short* qrow =
            base + (size_t)(half * 32 + wm + fr) * 1536 + h * 128;
        f32x4 s0 = {0.f, 0.f, 0.f, 0.f}, s1 = s0;
        #pragma unroll
        for (int k0 = 0; k0 < 128; k0 += 32) {
            bf16x8 a  = *(const bf16x8*)(qrow + k0 + kq);
            bf16x8 b0 = *(const bf16x8*)(Ks + (wn + fr) * 136 + k0 + kq);
            bf16x8 b1 = *(const bf16x8*)(Ks + (wn + 16 + fr) * 136 + k0 + kq);
            s0 = MFMA16(a, b0, s0, 0, 0, 0);
            s1 = MFMA16(a, b1, s1, 0, 0, 0);
        }
        const float scale = 0.08838834764831845f;
        #pragma unroll
        for (int r = 0; r < 4; ++r) {
            sc[(wm + crow + r) * 68 + wn + ccol]      = s0[r] * scale;
            sc[(wm + crow + r) * 68 + wn + 16 + ccol] = s1[r] * scale;
        }
    }
    __syncthreads();

    #pragma unroll
    for (int i = 0; i < 8; ++i) {
        int f = wave * 8 + i;
        float v = sc[f * 68 + lane];
        float mx = v;
        #pragma unroll
        for (int m = 32; m; m >>= 1) mx = fmaxf(mx, __shfl_xor(mx, m));
        float e = expf(v - mx);
        float sum = e;
        #pragma unroll
        for (int m = 32; m; m >>= 1) sum += __shfl_xor(sum, m);
        float a = e / sum;
        Pbf[f * 72 + lane] = f2bf(a);
        pws[(((size_t)b * 4 + h) * 64 + half * 32 + f) * 64 + lane] = a;
    }
    __syncthreads();

    {
        const int wn2 = (wave & 1) * 64;
        f32x4 o[4];
        #pragma unroll
        for (int t = 0; t < 4; ++t) o[t] = f32x4{0.f, 0.f, 0.f, 0.f};
        #pragma unroll
        for (int k0 = 0; k0 < 64; k0 += 32) {
            bf16x8 a = *(const bf16x8*)(Pbf + (wm + fr) * 72 + k0 + kq);
            #pragma unroll
            for (int t = 0; t < 4; ++t) {
                bf16x8 bv = *(const bf16x8*)(Vt + (wn2 + t * 16 + fr) * 72 + k0 + kq);
                o[t] = MFMA16(a, bv, o[t], 0, 0, 0);
            }
        }
        #pragma unroll
        for (int t = 0; t < 4; ++t)
            #pragma unroll
            for (int r = 0; r < 4; ++r) {
                size_t m = (size_t)b * 64 + half * 32 + wm + crow + r;
                int col = h * 128 + wn2 + t * 16 + ccol;
                x1o[m * 1024 + 512 + col] = f2bf(o[t][r]);
            }
    }
}

// ---------------------------------------------------------------------------
// fc1 GEMM only (pair MLPs moved to ln2pair): 512 blocks, BM=32, K=1024.
// ---------------------------------------------------------------------------
__global__ __launch_bounds__(256)
void w1gemm(const unsigned short* __restrict__ x1o,
            const unsigned short* __restrict__ W1cb,
            const float* __restrict__ beff, float* __restrict__ u) {
    __shared__ unsigned short Asl[32 * 64];
    __shared__ unsigned short Bsl[64 * 64];
    const int tid = threadIdx.x, wave = tid >> 6, lane = tid & 63;
    const int bx = blockIdx.x;
    const int m0 = (bx >> 3) * 32, n0 = (bx & 7) * 64;
    const int wm = (wave >> 1) * 16, wn = (wave & 1) * 32;
    const int fr = lane & 15, kq4 = lane >> 4;
    f32x4 acc[2] = {};
    for (int k0 = 0; k0 < 1024; k0 += 64) {
        {
            int r = tid >> 3, q = tid & 7;
            int col = (q ^ (r & 7)) * 8;
            __builtin_amdgcn_global_load_lds(
                (cv_global*)(x1o + (size_t)(m0 + r) * 1024 + k0 + col),
                (v_lds*)(Asl + wave * 512), 16, 0, 0);
        }
        #pragma unroll
        for (int c0 = 0; c0 < 512; c0 += 256) {
            int cc = c0 + tid, r = cc >> 3, q = cc & 7;
            int col = (q ^ (r & 7)) * 8;
            __builtin_amdgcn_global_load_lds(
                (cv_global*)(W1cb + (size_t)(n0 + r) * 1024 + k0 + col),
                (v_lds*)(Bsl + c0 * 8 + wave * 512), 16, 0, 0);
        }
        __syncthreads();
        #pragma unroll
        for (int j = 0; j < 2; ++j) {
            int kc = kq4 + j * 4;
            int rb0 = wn + fr, rb1 = wn + 16 + fr, ra = wm + fr;
            bf16x8 b0 = *(const bf16x8*)(Bsl + rb0 * 64 + (kc ^ (rb0 & 7)) * 8);
            bf16x8 b1 = *(const bf16x8*)(Bsl + rb1 * 64 + (kc ^ (rb1 & 7)) * 8);
            bf16x8 af = *(const bf16x8*)(Asl + ra * 64 + (kc ^ (ra & 7)) * 8);
            acc[0] = MFMA16(af, b0, acc[0], 0, 0, 0);
            acc[1] = MFMA16(af, b1, acc[1], 0, 0, 0);
        }
        __syncthreads();
    }
    const int crow = (lane >> 4) * 4, ccol = lane & 15;
    #pragma unroll
    for (int c = 0; c < 2; ++c) {
        int n = n0 + wn + c * 16 + ccol;
        float bj = beff[n];
        #pragma unroll
        for (int i = 0; i < 4; ++i) {
            size_t m = (size_t)(m0 + wm + crow + i);
            u[m * 512 + n] = fmaxf(acc[c][i] + bj, 0.f);
        }
    }
}

// ---------------------------------------------------------------------------
// bf16 MFMA GEMM (BM=32), used for fc2.
// ---------------------------------------------------------------------------
__global__ __launch_bounds__(256)
void gemm_w2(const unsigned short* __restrict__ A,
             const unsigned short* __restrict__ B,
             const float* __restrict__ bias, float* __restrict__ C) {
    __shared__ unsigned short Asl[32 * 64];
    __shared__ unsigned short Bsl[64 * 64];
    const int tid = threadIdx.x, wave = tid >> 6, lane = tid & 63;
    const int m0 = blockIdx.y * 32, n0 = blockIdx.x * 64;
    const int wm = (wave >> 1) * 16, wn = (wave & 1) * 32;
    const int fr = lane & 15, kq4 = lane >> 4;
    f32x4 acc[2] = {};
    for (int k0 = 0; k0 < 512; k0 += 64) {
        {
            int r = tid >> 3, q = tid & 7;
            int col = (q ^ (r & 7)) * 8;
            __builtin_amdgcn_global_load_lds(
                (cv_global*)(A + (size_t)(m0 + r) * 512 + k0 + col),
                (v_lds*)(Asl + wave * 512), 16, 0, 0);
        }
        #pragma unroll
        for (int c0 = 0; c0 < 512; c0 += 256) {
            int cc = c0 + tid, r = cc >> 3, q = cc & 7;
            int col = (q ^ (r & 7)) * 8;
            __builtin_amdgcn_global_load_lds(
                (cv_global*)(B + (size_t)(n0 + r) * 512 + k0 + col),
                (v_lds*)(Bsl + c0 * 8 + wave * 512), 16, 0, 0);
        }
        __syncthreads();
        #pragma unroll
        for (int j = 0; j < 2; ++j) {
            int kc = kq4 + j * 4;
            int rb0 = wn + fr, rb1 = wn + 16 + fr, ra = wm + fr;
            bf16x8 b0 = *(const bf16x8*)(Bsl + rb0 * 64 + (kc ^ (rb0 & 7)) * 8);
            bf16x8 b1 = *(const bf16x8*)(Bsl + rb1 * 64 + (kc ^ (rb1 & 7)) * 8);
            bf16x8 af = *(const bf16x8*)(Asl + ra * 64 + (kc ^ (ra & 7)) * 8);
            acc[0] = MFMA16(af, b0, acc[0], 0, 0, 0);
            acc[1] = MFMA16(af, b1, acc[1], 0, 0, 0);
        }
        __syncthreads();
    }
    const int crow = (lane >> 4) * 4, ccol = lane & 15;
    #pragma unroll
    for (int c = 0; c < 2; ++c) {
        int n = n0 + wn + c * 16 + ccol;
        float bj = bias[n];
        #pragma unroll
        for (int i = 0; i < 4; ++i) {
            size_t m = (size_t)(m0 + wm + crow + i);
            C[m * 512 + n] = fmaxf(acc[c][i] + bj, 0.f);
        }
    }
}

// ---------------------------------------------------------------------------
// out = LayerNorm(base + u) * g + be (+ optional bf16 copy). ln1 use.
// ---------------------------------------------------------------------------
__global__ __launch_bounds__(256)
void add_ln(const float* __restrict__ base, const float* __restrict__ u,
            const float* __restrict__ gam, const float* __restrict__ bet,
            float* __restrict__ out, unsigned short* __restrict__ outb) {
    const int row = blockIdx.x;
    const int tid = threadIdx.x, wave = tid >> 6, lane = tid & 63;
    const float* br = base + (size_t)row * EE;
    const float* ur = u + (size_t)row * EE;
    float t0 = br[tid] + ur[tid];
    float t1 = br[tid + 256] + ur[tid + 256];
    float s = t0 + t1, sq = t0 * t0 + t1 * t1;
    #pragma unroll
    for (int m = 32; m; m >>= 1) {
        s += __shfl_xor(s, m);
        sq += __shfl_xor(sq, m);
    }
    __shared__ float ssum[4], ssq[4];
    if (lane == 0) { ssum[wave] = s; ssq[wave] = sq; }
    __syncthreads();
    s = ssum[0] + ssum[1] + ssum[2] + ssum[3];
    sq = ssq[0] + ssq[1] + ssq[2] + ssq[3];
    float mean = s * (1.0f / EE);
    float var = sq * (1.0f / EE) - mean * mean;
    float inv = rsqrtf(var + LNEPS);
    float v0 = (t0 - mean) * inv * gam[tid] + bet[tid];
    float v1 = (t1 - mean) * inv * gam[tid + 256] + bet[tid + 256];
    float* orow = out + (size_t)row * EE;
    orow[tid] = v0;
    orow[tid + 256] = v1;
    if (outb) {
        unsigned short* obr = outb + (size_t)row * EE;
        obr[tid] = f2bf(v0);
        obr[tid + 256] = f2bf(v1);
    }
}

// ---------------------------------------------------------------------------
// Final launch: ln2 (blocks 0-2047) + pair MLPs (blocks 2048-4095).
// ---------------------------------------------------------------------------
__global__ __launch_bounds__(256)
void ln2pair(const float* __restrict__ hbuf, const float* __restrict__ u2,
             const float* __restrict__ gam, const float* __restrict__ bet,
             float* __restrict__ out,
             const unsigned short* __restrict__ Pb,
             const float* __restrict__ a1, const float* __restrict__ pws,
             const float* __restrict__ d1b1, const float* __restrict__ d1w2,
             const float* __restrict__ d1b2, const float* __restrict__ d2b1,
             const float* __restrict__ d2w2, const float* __restrict__ d2b2,
             float* __restrict__ x2_attn, float* __restrict__ out1,
             float* __restrict__ out2) {
    const int bx = blockIdx.x, tid = threadIdx.x;
    const int wave = tid >> 6, lane = tid & 63;
    __shared__ float ssum[4], ssq[4];

    if (bx < 2048) {
        const int row = bx;
        const float* br = hbuf + (size_t)row * EE;
        const float* ur = u2 + (size_t)row * EE;
        float t0 = br[tid] + ur[tid];
        float t1 = br[tid + 256] + ur[tid + 256];
        float s = t0 + t1, sq = t0 * t0 + t1 * t1;
        #pragma unroll
        for (int m = 32; m; m >>= 1) {
            s += __shfl_xor(s, m);
            sq += __shfl_xor(sq, m);
        }
        if (lane == 0) { ssum[wave] = s; ssq[wave] = sq; }
        __syncthreads();
        s = ssum[0] + ssum[1] + ssum[2] + ssum[3];
        sq = ssq[0] + ssq[1] + ssq[2] + ssq[3];
        float mean = s * (1.0f / EE);
        float var = sq * (1.0f / EE) - mean * mean;
        float inv = rsqrtf(var + LNEPS);
        float* orow = out + (size_t)row * EE;
        orow[tid] = (t0 - mean) * inv * gam[tid] + bet[tid];
        orow[tid + 256] = (t1 - mean) * inv * gam[tid + 256] + bet[tid + 256];
    } else {
        const int idx = bx - 2048;
        const int f = idx & 63, b = idx >> 6;
        const size_t row = (size_t)b * SS + f;
        const int c0 = lane * 2, c1 = lane * 2 + 1;

        const float p1f0 = bf2f(Pb[row * 256 + c0]),       p1f1 = bf2f(Pb[row * 256 + c1]);
        const float p2f0 = bf2f(Pb[row * 256 + 128 + c0]), p2f1 = bf2f(Pb[row * 256 + 128 + c1]);
        const float w10 = d1w2[c0], w11 = d1w2[c1];
        const float w20 = d2w2[c0], w21 = d2w2[c1];
        const float b10 = d1b1[c0], b11 = d1b1[c1];
        const float b20 = d2b1[c0], b21 = d2b1[c1];
        const float bb1 = d1b2[0], bb2 = d2b2[0];

        const float* a1r = a1 + row * SS;
        const float* ph0 = pws + (((size_t)b * 4 + 0) * 64 + f) * 64;
        const float* ph1 = pws + (((size_t)b * 4 + 1) * 64 + f) * 64;
        const float* ph2 = pws + (((size_t)b * 4 + 2) * 64 + f) * 64;
        const float* ph3 = pws + (((size_t)b * 4 + 3) * 64 + f) * 64;
        const size_t bbase = (size_t)b * SS * 256;

        for (int g = wave; g < 64; g += 4) {
            float aa1 = a1r[g];
            float aa2 = 0.25f * (ph0[g] + ph1[g] + ph2[g] + ph3[g]);
            float q10 = bf2f(Pb[bbase + g * 256 + c0]);
            float q11 = bf2f(Pb[bbase + g * 256 + c1]);
            float q20 = bf2f(Pb[bbase + g * 256 + 128 + c0]);
            float q21 = bf2f(Pb[bbase + g * 256 + 128 + c1]);
            float h10 = fmaxf(aa1 * (q10 - p1f0) + b10, 0.f);
            float h11 = fmaxf(aa1 * (q11 - p1f1) + b11, 0.f);
            float h20 = fmaxf(aa2 * (q20 - p2f0) + b20, 0.f);
            float h21 = fmaxf(aa2 * (q21 - p2f1) + b21, 0.f);
            float s1 = w10 * h10 + w11 * h11;
            float s2 = w20 * h20 + w21 * h21;
            #pragma unroll
            for (int m = 32; m; m >>= 1) {
                s1 += __shfl_xor(s1, m);
                s2 += __shfl_xor(s2, m);
            }
            if (lane == 0) {
                x2_attn[row * SS + g] = aa2;
                out1[row * SS + g] = fmaxf(s1 + bb1, 0.f);
                out2[row * SS + g] = fmaxf(s2 + bb2, 0.f);
            }
        }
    }
}

// ---------------------------------------------------------------------------
extern "C" void kernel_launch(void* const* d_in, const int* in_sizes, int n_in,
                              void* d_out, int out_size, void* d_ws,
                              size_t ws_size, hipStream_t stream) {
    const float* x    = (const float*)d_in[0];
    const float* Wqkv = (const float*)d_in[1];
    const float* bqkv = (const float*)d_in[2];
    const float* Wo   = (const float*)d_in[3];
    const float* bo   = (const float*)d_in[4];
    const float* W1   = (const float*)d_in[5];
    const float* b1   = (const float*)d_in[6];
    const float* W2   = (const float*)d_in[7];
    const float* b2   = (const float*)d_in[8];
    const float* g1   = (const float*)d_in[9];
    const float* be1  = (const float*)d_in[10];
    const float* g2   = (const float*)d_in[11];
    const float* be2  = (const float*)d_in[12];
    const float* d1W1 = (const float*)d_in[13];
    const float* d1b1 = (const float*)d_in[14];
    const float* d1W2 = (const float*)d_in[15];
    const float* d1b2 = (const float*)d_in[16];
    const float* d2W1 = (const float*)d_in[17];
    const float* d2b1 = (const float*)d_in[18];
    const float* d2W2 = (const float*)d_in[19];
    const float* d2b2 = (const float*)d_in[20];

    float* out      = (float*)d_out;
    float* out_main = out;
    float* x1_attn  = out + 1048576;
    float* x2_attn  = out + 1048576 + 131072;
    float* diff1    = out + 1048576 + 2 * 131072;
    float* diff2    = out + 1048576 + 3 * 131072;

    float* ws    = (float*)d_ws;
    float* u_buf = ws;                              // 2048*512
    float* h_buf = ws + 1048576;                    // 2048*512
    float* pws   = ws + 2097152;                    // 32*4*64*64
    float* b_eff = ws + 2621440;                    // 512
    unsigned short* Pl2 = (unsigned short*)(ws + 2621952);  // 2048*64 bf16
    unsigned short* bb  = (unsigned short*)(ws + 2687488);

    unsigned short* xb    = bb + XB_O;
    unsigned short* Wfull = bb + WFULL_O;
    unsigned short* W1cb  = bb + W1CB_O;
    unsigned short* W2b   = bb + W2B_O;
    unsigned short* qkvb  = bb + QKVB_O;
    unsigned short* x1o   = bb + X1O_O;
    unsigned short* hb    = bb + HB_O;
    unsigned short* Pb    = bb + PB_O;

    // 1: convert + Wc prep + b_eff + Gram L2-attention (2 blocks/batch)
    mega1<<<1540, 256, 0, stream>>>(x, Wqkv, Wo, W1, W2, d1W1, d2W1, b1, bo,
                                    bb, b_eff, x1_attn, Pl2);

    // 2: [qkv | P] = xb @ Wfull^T  +  x1 = Pl2 @ xb  (x1 -> x1o[:, :512])
    gemm_qkvp<<<dim3(36, 32), 256, 0, stream>>>(xb, Wfull, bqkv, qkvb, Pb,
                                                Pl2, x1o);

    // 3: attention; o -> x1o[:,512:], probs -> pws
    mha_attn<<<dim3(8, 32), 256, 0, stream>>>(qkvb, x1o, pws);

    // 4: u = relu([x1|o] @ [W1a|Wc]^T + b_eff)   (GEMM only, 2/CU)
    w1gemm<<<512, 256, 0, stream>>>(x1o, W1cb, b_eff, u_buf);

    // 5: h = LN(x + u) -> h_buf (f32) + hb (bf16)
    add_ln<<<2048, 256, 0, stream>>>(x, u_buf, g1, be1, h_buf, hb);

    // 6: u = relu(h @ W2^T + b2)
    gemm_w2<<<dim3(8, 64), 256, 0, stream>>>(hb, W2b, b2, u_buf);

    // 7: out = LN2(h + u)  +  pair MLPs
    ln2pair<<<4096, 256, 0, stream>>>(h_buf, u_buf, g2, be2, out_main, Pb,
                                      x1_attn, pws, d1b1, d1W2, d1b2, d2b1,
                                      d2W2, d2b2, x2_attn, diff1, diff2);
}

// Round 12
// 175.790 us; speedup vs baseline: 1.0245x; 1.0245x over previous
//
#include <hip/hip_runtime.h>
#include <math.h>

// Problem constants
#define SS 64
#define EE 512
#define L2T 13.544f
#define LNEPS 1e-5f

using bf16x8 = __attribute__((ext_vector_type(8))) __bf16;
using u16x8  = __attribute__((ext_vector_type(8))) unsigned short;
using f32x4  = __attribute__((ext_vector_type(4))) float;

typedef const void __attribute__((address_space(1))) cv_global;
typedef void __attribute__((address_space(3))) v_lds;

__device__ inline unsigned short f2bf(float f) {
    union { float f; unsigned u; } v; v.f = f;
    unsigned r = v.u + 0x7fff + ((v.u >> 16) & 1);
    return (unsigned short)(r >> 16);
}
__device__ inline float bf2f(unsigned short h) {
    union { unsigned u; float f; } v; v.u = (unsigned)h << 16;
    return v.f;
}

#define MFMA16 __builtin_amdgcn_mfma_f32_16x16x32_bf16

// bb (ushort offsets):
#define XB_O    0
#define WFULL_O 1048576
#define W1CB_O  1966080
#define W2B_O   2490368
#define QKVB_O  2752512
#define X1O_O   5898240
#define HB_O    7995392
#define PB_O    9043968

// ---------------------------------------------------------------------------
// MEGA-1: weight convert (0-1407) + Wc=W1b@Wo prep (1408-1471) + b_eff
// (1472-1475) + Gram-based L2 attention (1476-1539; 2 blocks/batch).
// ---------------------------------------------------------------------------
__global__ __launch_bounds__(256)
void mega1(const float* __restrict__ x, const float* __restrict__ Wqkv,
           const float* __restrict__ Wo, const float* __restrict__ W1,
           const float* __restrict__ W2, const float* __restrict__ d1,
           const float* __restrict__ d2, const float* __restrict__ b1,
           const float* __restrict__ bo, unsigned short* __restrict__ bb,
           float* __restrict__ b_eff, float* __restrict__ x1_attn,
           unsigned short* __restrict__ Pl2) {
    const int bx = blockIdx.x, tid = threadIdx.x;
    __shared__ __align__(16) char smem[36096];

    if (bx < 1408) {
        int i = bx * 256 + tid;
        ushort4* dst4 = (ushort4*)bb;
        const float4* s; int di;
        if (i < 196608)      { s = (const float4*)Wqkv + i;          di = WFULL_O/4 + i; }
        else if (i < 212992) { int j = i-196608; s = (const float4*)d1 + j; di = WFULL_O/4 + 196608 + j; }
        else if (i < 229376) { int j = i-212992; s = (const float4*)d2 + j; di = WFULL_O/4 + 212992 + j; }
        else if (i < 294912) { int j = i-229376; s = (const float4*)W2 + j; di = W2B_O/4 + j; }
        else                 { int j = i-294912; int r = j>>7, cq = j&127;
                               s = (const float4*)W1 + r*256 + cq;   di = W1CB_O/4 + r*256 + cq; }
        float4 v = *s;
        ushort4 o;
        o.x = f2bf(v.x); o.y = f2bf(v.y); o.z = f2bf(v.z); o.w = f2bf(v.w);
        dst4[di] = o;
    } else if (bx < 1472) {
        const int tb = bx - 1408;
        const int m0 = (tb >> 3) * 64, n0 = (tb & 7) * 64;
        unsigned short* Asl = (unsigned short*)smem;   // [64][40]
        unsigned short* Bsl = Asl + 64 * 40;           // [64][40]
        const int wave = tid >> 6, lane = tid & 63;
        const int wm = (wave >> 1) * 32, wn = (wave & 1) * 32;
        const int fr = lane & 15, kq = (lane >> 4) * 8;
        f32x4 acc[2][2] = {};
        for (int k0 = 0; k0 < 512; k0 += 32) {
            {
                int m = tid >> 2, kk = (tid & 3) * 8;
                const float* src = W1 + (size_t)(m0 + m) * 1024 + 512 + k0 + kk;
                float4 v0 = *(const float4*)src, v1 = *(const float4*)(src + 4);
                u16x8 t = {f2bf(v0.x), f2bf(v0.y), f2bf(v0.z), f2bf(v0.w),
                           f2bf(v1.x), f2bf(v1.y), f2bf(v1.z), f2bf(v1.w)};
                *(u16x8*)(Asl + m * 40 + kk) = t;
            }
            {
                int k = tid >> 3, jq = (tid & 7) * 8;
                const float* src = Wo + (size_t)(k0 + k) * 512 + n0 + jq;
                float4 v0 = *(const float4*)src, v1 = *(const float4*)(src + 4);
                float vv[8] = {v0.x, v0.y, v0.z, v0.w, v1.x, v1.y, v1.z, v1.w};
                #pragma unroll
                for (int e = 0; e < 8; ++e) Bsl[(jq + e) * 40 + k] = f2bf(vv[e]);
            }
            __syncthreads();
            bf16x8 a0 = *(const bf16x8*)(Asl + (wm + fr) * 40 + kq);
            bf16x8 a1 = *(const bf16x8*)(Asl + (wm + 16 + fr) * 40 + kq);
            bf16x8 b0 = *(const bf16x8*)(Bsl + (wn + fr) * 40 + kq);
            bf16x8 b1 = *(const bf16x8*)(Bsl + (wn + 16 + fr) * 40 + kq);
            acc[0][0] = MFMA16(a0, b0, acc[0][0], 0, 0, 0);
            acc[0][1] = MFMA16(a0, b1, acc[0][1], 0, 0, 0);
            acc[1][0] = MFMA16(a1, b0, acc[1][0], 0, 0, 0);
            acc[1][1] = MFMA16(a1, b1, acc[1][1], 0, 0, 0);
            __syncthreads();
        }
        unsigned short* W1cb = bb + W1CB_O;
        const int crow = (lane >> 4) * 4, ccol = lane & 15;
        #pragma unroll
        for (int r2 = 0; r2 < 2; ++r2)
            #pragma unroll
            for (int c2 = 0; c2 < 2; ++c2)
                #pragma unroll
                for (int i = 0; i < 4; ++i) {
                    int m = m0 + wm + r2 * 16 + crow + i;
                    int j = n0 + wn + c2 * 16 + ccol;
                    W1cb[(size_t)m * 1024 + 512 + j] = f2bf(acc[r2][c2][i]);
                }
    } else if (bx < 1476) {
        int n = (bx - 1472) * 128 + (tid >> 1);
        int kh = (tid & 1) * 256;
        float s = 0.f;
        for (int k = 0; k < 256; ++k)
            s += W1[(size_t)n * 1024 + 512 + kh + k] * bo[kh + k];
        s += __shfl_xor(s, 1);
        if ((tid & 1) == 0) b_eff[n] = b1[n] + s;
    } else {
        // Gram-based L2 attention (bf16x3 split), 2 blocks/batch (32 rows ea).
        const int idx = bx - 1476;
        const int b = idx >> 1, hf = idx & 1;
        unsigned short* Xhi = (unsigned short*)smem;   // [64][72]
        unsigned short* Xlo = Xhi + 64 * 72;           // [64][72]
        float* sc    = (float*)(smem + 18432);         // [32][68]
        float* norms = (float*)(smem + 27136);         // [64] (fp32 exact)
        const int wave = tid >> 6, lane = tid & 63;
        const int fr = lane & 15;
        const int srow = tid >> 2, scq = (tid & 3) * 16;
        const int wmg = hf * 32 + (wave >> 1) * 16;
        const int wn = (wave & 1) * 32;

        f32x4 acc[2] = {};
        float nsq = 0.f;
        const float* xrow = x + (size_t)b * 32768;
        unsigned short* xbg = bb + XB_O + (size_t)b * 32768;

        for (int k0 = 0; k0 < 512; k0 += 64) {
            const float* src = xrow + srow * 512 + k0 + scq;
            u16x8 hi0, hi1, lo0, lo1;
            #pragma unroll
            for (int e = 0; e < 8; ++e) {
                float v = src[e];
                nsq += v * v;
                unsigned short h = f2bf(v);
                hi0[e] = h; lo0[e] = f2bf(v - bf2f(h));
            }
            #pragma unroll
            for (int e = 0; e < 8; ++e) {
                float v = src[8 + e];
                nsq += v * v;
                unsigned short h = f2bf(v);
                hi1[e] = h; lo1[e] = f2bf(v - bf2f(h));
            }
            *(u16x8*)(Xhi + srow * 72 + scq)     = hi0;
            *(u16x8*)(Xhi + srow * 72 + scq + 8) = hi1;
            *(u16x8*)(Xlo + srow * 72 + scq)     = lo0;
            *(u16x8*)(Xlo + srow * 72 + scq + 8) = lo1;
            if (hf == 0) {
                *(u16x8*)(xbg + srow * 512 + k0 + scq)     = hi0;
                *(u16x8*)(xbg + srow * 512 + k0 + scq + 8) = hi1;
            }
            __syncthreads();
            #pragma unroll
            for (int j = 0; j < 2; ++j) {
                int kk = j * 32 + (lane >> 4) * 8;
                bf16x8 ah = *(const bf16x8*)(Xhi + (wmg + fr) * 72 + kk);
                bf16x8 al = *(const bf16x8*)(Xlo + (wmg + fr) * 72 + kk);
                #pragma unroll
                for (int c2 = 0; c2 < 2; ++c2) {
                    bf16x8 bh = *(const bf16x8*)(Xhi + (wn + c2 * 16 + fr) * 72 + kk);
                    bf16x8 bl = *(const bf16x8*)(Xlo + (wn + c2 * 16 + fr) * 72 + kk);
                    acc[c2] = MFMA16(ah, bh, acc[c2], 0, 0, 0);
                    acc[c2] = MFMA16(ah, bl, acc[c2], 0, 0, 0);
                    acc[c2] = MFMA16(al, bh, acc[c2], 0, 0, 0);
                }
            }
            __syncthreads();
        }
        nsq += __shfl_xor(nsq, 1);
        nsq += __shfl_xor(nsq, 2);
        if ((tid & 3) == 0) norms[srow] = nsq;
        const int crow = (lane >> 4) * 4, ccol = lane & 15;
        #pragma unroll
        for (int c2 = 0; c2 < 2; ++c2)
            #pragma unroll
            for (int i = 0; i < 4; ++i)
                sc[(wmg - hf * 32 + crow + i) * 68 + wn + c2 * 16 + ccol] =
                    acc[c2][i];
        __syncthreads();
        #pragma unroll
        for (int i = 0; i < 8; ++i) {
            int lr = wave * 8 + i;
            int f = hf * 32 + lr;
            float nf = norms[f];
            float val = (2.f * sc[lr * 68 + lane] - nf - norms[lane]) * (1.0f / L2T);
            float mx = val;
            #pragma unroll
            for (int m = 32; m; m >>= 1) mx = fmaxf(mx, __shfl_xor(mx, m));
            float e = expf(val - mx);
            float sum = e;
            #pragma unroll
            for (int m = 32; m; m >>= 1) sum += __shfl_xor(sum, m);
            float a = e / sum;
            x1_attn[((size_t)b * 64 + f) * 64 + lane] = a;
            Pl2[((size_t)b * 64 + f) * 64 + lane] = f2bf(a);
        }
    }
}

// ---------------------------------------------------------------------------
// Fused qkv + P GEMM + x1-apply.  Wfull = [Wqkv(1536) ; d1W1 ; d2W1].
// bx<24 -> qkvb; 24<=bx<28 -> Pb; bx>=28 -> x1 = Pl2 @ xb (per (b, e-tile)).
// ---------------------------------------------------------------------------
__global__ __launch_bounds__(256)
void gemm_qkvp(const unsigned short* __restrict__ A,
               const unsigned short* __restrict__ B,
               const float* __restrict__ bias,
               unsigned short* __restrict__ Cq, unsigned short* __restrict__ Cp,
               const unsigned short* __restrict__ Pl2,
               unsigned short* __restrict__ x1o) {
    __shared__ unsigned short qsm[8704];
    const int tid = threadIdx.x, wave = tid >> 6, lane = tid & 63;
    const int fr = lane & 15;
    const int crow = (lane >> 4) * 4, ccol = lane & 15;

    if (blockIdx.x < 28) {
        unsigned short* Asl = qsm;
        unsigned short* Bsl = qsm + 4096;
        const int m0 = blockIdx.y * 64, n0 = blockIdx.x * 64;
        const int wm = (wave >> 1) * 32, wn = (wave & 1) * 32;
        f32x4 acc[2][2] = {};

        for (int k0 = 0; k0 < 512; k0 += 64) {
            #pragma unroll
            for (int c0 = 0; c0 < 512; c0 += 256) {
                int cc = c0 + tid, r = cc >> 3, q = cc & 7;
                int col = (q ^ (r & 7)) * 8;
                __builtin_amdgcn_global_load_lds(
                    (cv_global*)(A + (size_t)(m0 + r) * 512 + k0 + col),
                    (v_lds*)(Asl + c0 * 8 + wave * 512), 16, 0, 0);
            }
            #pragma unroll
            for (int c0 = 0; c0 < 512; c0 += 256) {
                int cc = c0 + tid, r = cc >> 3, q = cc & 7;
                int col = (q ^ (r & 7)) * 8;
                __builtin_amdgcn_global_load_lds(
                    (cv_global*)(B + (size_t)(n0 + r) * 512 + k0 + col),
                    (v_lds*)(Bsl + c0 * 8 + wave * 512), 16, 0, 0);
            }
            __syncthreads();
            #pragma unroll
            for (int j = 0; j < 2; ++j) {
                int kc = (lane >> 4) + j * 4;
                int rb0 = wn + fr, rb1 = wn + 16 + fr;
                bf16x8 b0 = *(const bf16x8*)(Bsl + rb0 * 64 + (kc ^ (rb0 & 7)) * 8);
                bf16x8 b1 = *(const bf16x8*)(Bsl + rb1 * 64 + (kc ^ (rb1 & 7)) * 8);
                #pragma unroll
                for (int r = 0; r < 2; ++r) {
                    int ra = wm + r * 16 + fr;
                    bf16x8 af = *(const bf16x8*)(Asl + ra * 64 + (kc ^ (ra & 7)) * 8);
                    acc[r][0] = MFMA16(af, b0, acc[r][0], 0, 0, 0);
                    acc[r][1] = MFMA16(af, b1, acc[r][1], 0, 0, 0);
                }
            }
            __syncthreads();
        }

        if (blockIdx.x < 24) {
            float bj0 = bias[n0 + wn + ccol], bj1 = bias[n0 + wn + 16 + ccol];
            #pragma unroll
            for (int r = 0; r < 2; ++r)
                #pragma unroll
                for (int c = 0; c < 2; ++c) {
                    float bj = c ? bj1 : bj0;
                    #pragma unroll
                    for (int i = 0; i < 4; ++i) {
                        size_t m = (size_t)(m0 + wm + r * 16 + crow + i);
                        int n = n0 + wn + c * 16 + ccol;
                        Cq[m * 1536 + n] = f2bf(acc[r][c][i] + bj);
                    }
                }
        } else {
            int p0 = n0 - 1536;
            #pragma unroll
            for (int r = 0; r < 2; ++r)
                #pragma unroll
                for (int c = 0; c < 2; ++c)
                    #pragma unroll
                    for (int i = 0; i < 4; ++i) {
                        size_t m = (size_t)(m0 + wm + r * 16 + crow + i);
                        int n = p0 + wn + c * 16 + ccol;
                        Cp[m * 256 + n] = f2bf(acc[r][c][i]);
                    }
        }
    } else {
        // x1[b, :, e0:e0+64] = Pl2 @ xb
        const int e0 = (blockIdx.x - 28) * 64;
        const int b = blockIdx.y;
        unsigned short* Ap = qsm;            // [64][68]
        unsigned short* Xt = qsm + 64 * 68;  // [64][68]
        {
            int row = tid >> 2, cq2 = (tid & 3) * 16;
            const unsigned short* src = Pl2 + (size_t)b * 4096 + row * 64 + cq2;
            *(u16x8*)(Ap + row * 68 + cq2)     = *(const u16x8*)src;
            *(u16x8*)(Ap + row * 68 + cq2 + 8) = *(const u16x8*)(src + 8);
        }
        {
            int g = tid >> 2, cq2 = (tid & 3) * 16;
            const unsigned short* src = A + (size_t)b * 32768 + g * 512 + e0 + cq2;
            u16x8 v0 = *(const u16x8*)src, v1 = *(const u16x8*)(src + 8);
            #pragma unroll
            for (int e = 0; e < 8; ++e) Xt[(cq2 + e) * 68 + g] = v0[e];
            #pragma unroll
            for (int e = 0; e < 8; ++e) Xt[(cq2 + 8 + e) * 68 + g] = v1[e];
        }
        __syncthreads();
        const int wm2 = wave * 16, kq = (lane >> 4) * 8;
        f32x4 o[4] = {};
        #pragma unroll
        for (int j = 0; j < 2; ++j) {
            int kk = j * 32 + kq;
            bf16x8 a = *(const bf16x8*)(Ap + (wm2 + fr) * 68 + kk);
            #pragma unroll
            for (int t = 0; t < 4; ++t) {
                bf16x8 bv = *(const bf16x8*)(Xt + (t * 16 + fr) * 68 + kk);
                o[t] = MFMA16(a, bv, o[t], 0, 0, 0);
            }
        }
        #pragma unroll
        for (int t = 0; t < 4; ++t)
            #pragma unroll
            for (int i = 0; i < 4; ++i) {
                size_t m = (size_t)b * 64 + wm2 + crow + i;
                x1o[m * 1024 + e0 + t * 16 + ccol] = f2bf(o[t][i]);
            }
    }
}

// ---------------------------------------------------------------------------
// MFMA attention. Block per (b, h, half). o written straight into x1o[:,512:].
// ---------------------------------------------------------------------------
__global__ __launch_bounds__(256)
void mha_attn(const unsigned short* __restrict__ qkv,
              unsigned short* __restrict__ x1o, float* __restrict__ pws) {
    const int hh = blockIdx.x;
    const int h = hh >> 1, half = hh & 1;
    const int b = blockIdx.y;
    const int tid = threadIdx.x, wave = tid >> 6, lane = tid & 63;

    __shared__ unsigned short Qs[32 * 136];
    __shared__ unsigned short Ks[64 * 136];
    __shared__ unsigned short Vt[128 * 72];
    __shared__ float sc[32 * 68];
    __shared__ unsigned short Pbf[32 * 72];

    const unsigned short* base = qkv + (size_t)b * 64 * 1536;
    {
        int row = tid >> 3, col = (tid & 7) * 16;
        const unsigned short* src = base + (half * 32 + row) * 1536 + h * 128 + col;
        *(u16x8*)(Qs + row * 136 + col)     = *(const u16x8*)(src);
        *(u16x8*)(Qs + row * 136 + col + 8) = *(const u16x8*)(src + 8);
    }
    {
        int row = tid >> 2, col = (tid & 3) * 32;
        const unsigned short* src = base + row * 1536 + 512 + h * 128 + col;
        #pragma unroll
        for (int j = 0; j < 4; ++j)
            *(u16x8*)(Ks + row * 136 + col + j * 8) = *(const u16x8*)(src + j * 8);
    }
    {
        int g = tid >> 2, col = (tid & 3) * 32;
        const unsigned short* src = base + g * 1536 + 1024 + h * 128 + col;
        #pragma unroll
        for (int j = 0; j < 4; ++j) {
            u16x8 v = *(const u16x8*)(src + j * 8);
            #pragma unroll
            for (int e = 0; e < 8; ++e)
                Vt[(col + j * 8 + e) * 72 + g] = v[e];
        }
    }
    __syncthreads();

    const int fr = lane & 15, kq = (lane >> 4) * 8;
    const int crow = (lane >> 4) * 4, ccol = lane & 15;
    const int wm = (wave >> 1) * 16;
    {
        const int wn = (wave & 1) * 32;
        f32x4 s0 = {0.f, 0.f, 0.f, 0.f}, s1 = s0;
        #pragma unroll
        for (int k0 = 0; k0 < 128; k0 += 32) {
            bf16x8 a  = *(const bf16x8*)(Qs + (wm + fr) * 136 + k0 + kq);
            bf16x8 b0 = *(const bf16x8*)(Ks + (wn + fr) * 136 + k0 + kq);
            bf16x8 b1 = *(const bf16x8*)(Ks + (wn + 16 + fr) * 136 + k0 + kq);
            s0 = MFMA16(a, b0, s0, 0, 0, 0);
            s1 = MFMA16(a, b1, s1, 0, 0, 0);
        }
        const float scale = 0.08838834764831845f;
        #pragma unroll
        for (int r = 0; r < 4; ++r) {
            sc[(wm + crow + r) * 68 + wn + ccol]      = s0[r] * scale;
            sc[(wm + crow + r) * 68 + wn + 16 + ccol] = s1[r] * scale;
        }
    }
    __syncthreads();

    #pragma unroll
    for (int i = 0; i < 8; ++i) {
        int f = wave * 8 + i;
        float v = sc[f * 68 + lane];
        float mx = v;
        #pragma unroll
        for (int m = 32; m; m >>= 1) mx = fmaxf(mx, __shfl_xor(mx, m));
        float e = expf(v - mx);
        float sum = e;
        #pragma unroll
        for (int m = 32; m; m >>= 1) sum += __shfl_xor(sum, m);
        float a = e / sum;
        Pbf[f * 72 + lane] = f2bf(a);
        pws[(((size_t)b * 4 + h) * 64 + half * 32 + f) * 64 + lane] = a;
    }
    __syncthreads();

    {
        const int wn2 = (wave & 1) * 64;
        f32x4 o[4];
        #pragma unroll
        for (int t = 0; t < 4; ++t) o[t] = f32x4{0.f, 0.f, 0.f, 0.f};
        #pragma unroll
        for (int k0 = 0; k0 < 64; k0 += 32) {
            bf16x8 a = *(const bf16x8*)(Pbf + (wm + fr) * 72 + k0 + kq);
            #pragma unroll
            for (int t = 0; t < 4; ++t) {
                bf16x8 bv = *(const bf16x8*)(Vt + (wn2 + t * 16 + fr) * 72 + k0 + kq);
                o[t] = MFMA16(a, bv, o[t], 0, 0, 0);
            }
        }
        #pragma unroll
        for (int t = 0; t < 4; ++t)
            #pragma unroll
            for (int r = 0; r < 4; ++r) {
                size_t m = (size_t)b * 64 + half * 32 + wm + crow + r;
                int col = h * 128 + wn2 + t * 16 + ccol;
                x1o[m * 1024 + 512 + col] = f2bf(o[t][r]);
            }
    }
}

// ---------------------------------------------------------------------------
// Fused fc1 GEMM (blocks 0-511) + pair MLPs (blocks 512-2559).
// ---------------------------------------------------------------------------
__global__ __launch_bounds__(256)
void w1pair(const unsigned short* __restrict__ x1o,
            const unsigned short* __restrict__ W1cb,
            const float* __restrict__ beff, float* __restrict__ u,
            const unsigned short* __restrict__ Pb,
            const float* __restrict__ a1, const float* __restrict__ pws,
            const float* __restrict__ d1b1, const float* __restrict__ d1w2,
            const float* __restrict__ d1b2, const float* __restrict__ d2b1,
            const float* __restrict__ d2w2, const float* __restrict__ d2b2,
            float* __restrict__ x2_attn, float* __restrict__ out1,
            float* __restrict__ out2) {
    __shared__ unsigned short Asl[32 * 64];
    __shared__ unsigned short Bsl[64 * 64];
    const int bx = blockIdx.x, tid = threadIdx.x;
    const int wave = tid >> 6, lane = tid & 63;

    if (bx < 512) {
        const int m0 = (bx >> 3) * 32, n0 = (bx & 7) * 64;
        const int wm = (wave >> 1) * 16, wn = (wave & 1) * 32;
        const int fr = lane & 15, kq4 = lane >> 4;
        f32x4 acc[2] = {};
        for (int k0 = 0; k0 < 1024; k0 += 64) {
            {
                int r = tid >> 3, q = tid & 7;
                int col = (q ^ (r & 7)) * 8;
                __builtin_amdgcn_global_load_lds(
                    (cv_global*)(x1o + (size_t)(m0 + r) * 1024 + k0 + col),
                    (v_lds*)(Asl + wave * 512), 16, 0, 0);
            }
            #pragma unroll
            for (int c0 = 0; c0 < 512; c0 += 256) {
                int cc = c0 + tid, r = cc >> 3, q = cc & 7;
                int col = (q ^ (r & 7)) * 8;
                __builtin_amdgcn_global_load_lds(
                    (cv_global*)(W1cb + (size_t)(n0 + r) * 1024 + k0 + col),
                    (v_lds*)(Bsl + c0 * 8 + wave * 512), 16, 0, 0);
            }
            __syncthreads();
            #pragma unroll
            for (int j = 0; j < 2; ++j) {
                int kc = kq4 + j * 4;
                int rb0 = wn + fr, rb1 = wn + 16 + fr, ra = wm + fr;
                bf16x8 b0 = *(const bf16x8*)(Bsl + rb0 * 64 + (kc ^ (rb0 & 7)) * 8);
                bf16x8 b1 = *(const bf16x8*)(Bsl + rb1 * 64 + (kc ^ (rb1 & 7)) * 8);
                bf16x8 af = *(const bf16x8*)(Asl + ra * 64 + (kc ^ (ra & 7)) * 8);
                acc[0] = MFMA16(af, b0, acc[0], 0, 0, 0);
                acc[1] = MFMA16(af, b1, acc[1], 0, 0, 0);
            }
            __syncthreads();
        }
        const int crow = (lane >> 4) * 4, ccol = lane & 15;
        #pragma unroll
        for (int c = 0; c < 2; ++c) {
            int n = n0 + wn + c * 16 + ccol;
            float bj = beff[n];
            #pragma unroll
            for (int i = 0; i < 4; ++i) {
                size_t m = (size_t)(m0 + wm + crow + i);
                u[m * 512 + n] = fmaxf(acc[c][i] + bj, 0.f);
            }
        }
    } else {
        const int idx = bx - 512;
        const int f = idx & 63, b = idx >> 6;
        const size_t row = (size_t)b * SS + f;
        const int c0 = lane * 2, c1 = lane * 2 + 1;

        const float p1f0 = bf2f(Pb[row * 256 + c0]),       p1f1 = bf2f(Pb[row * 256 + c1]);
        const float p2f0 = bf2f(Pb[row * 256 + 128 + c0]), p2f1 = bf2f(Pb[row * 256 + 128 + c1]);
        const float w10 = d1w2[c0], w11 = d1w2[c1];
        const float w20 = d2w2[c0], w21 = d2w2[c1];
        const float b10 = d1b1[c0], b11 = d1b1[c1];
        const float b20 = d2b1[c0], b21 = d2b1[c1];
        const float bb1 = d1b2[0], bb2 = d2b2[0];

        const float* a1r = a1 + row * SS;
        const float* ph0 = pws + (((size_t)b * 4 + 0) * 64 + f) * 64;
        const float* ph1 = pws + (((size_t)b * 4 + 1) * 64 + f) * 64;
        const float* ph2 = pws + (((size_t)b * 4 + 2) * 64 + f) * 64;
        const float* ph3 = pws + (((size_t)b * 4 + 3) * 64 + f) * 64;
        const size_t bbase = (size_t)b * SS * 256;

        for (int g = wave; g < 64; g += 4) {
            float aa1 = a1r[g];
            float aa2 = 0.25f * (ph0[g] + ph1[g] + ph2[g] + ph3[g]);
            float q10 = bf2f(Pb[bbase + g * 256 + c0]);
            float q11 = bf2f(Pb[bbase + g * 256 + c1]);
            float q20 = bf2f(Pb[bbase + g * 256 + 128 + c0]);
            float q21 = bf2f(Pb[bbase + g * 256 + 128 + c1]);
            float h10 = fmaxf(aa1 * (q10 - p1f0) + b10, 0.f);
            float h11 = fmaxf(aa1 * (q11 - p1f1) + b11, 0.f);
            float h20 = fmaxf(aa2 * (q20 - p2f0) + b20, 0.f);
            float h21 = fmaxf(aa2 * (q21 - p2f1) + b21, 0.f);
            float s1 = w10 * h10 + w11 * h11;
            float s2 = w20 * h20 + w21 * h21;
            #pragma unroll
            for (int m = 32; m; m >>= 1) {
                s1 += __shfl_xor(s1, m);
                s2 += __shfl_xor(s2, m);
            }
            if (lane == 0) {
                x2_attn[row * SS + g] = aa2;
                out1[row * SS + g] = fmaxf(s1 + bb1, 0.f);
                out2[row * SS + g] = fmaxf(s2 + bb2, 0.f);
            }
        }
    }
}

// ---------------------------------------------------------------------------
// bf16 MFMA GEMM (BM=32), used for fc2.
// ---------------------------------------------------------------------------
__global__ __launch_bounds__(256)
void gemm_w2(const unsigned short* __restrict__ A,
             const unsigned short* __restrict__ B,
             const float* __restrict__ bias, float* __restrict__ C) {
    __shared__ unsigned short Asl[32 * 64];
    __shared__ unsigned short Bsl[64 * 64];
    const int tid = threadIdx.x, wave = tid >> 6, lane = tid & 63;
    const int m0 = blockIdx.y * 32, n0 = blockIdx.x * 64;
    const int wm = (wave >> 1) * 16, wn = (wave & 1) * 32;
    const int fr = lane & 15, kq4 = lane >> 4;
    f32x4 acc[2] = {};
    for (int k0 = 0; k0 < 512; k0 += 64) {
        {
            int r = tid >> 3, q = tid & 7;
            int col = (q ^ (r & 7)) * 8;
            __builtin_amdgcn_global_load_lds(
                (cv_global*)(A + (size_t)(m0 + r) * 512 + k0 + col),
                (v_lds*)(Asl + wave * 512), 16, 0, 0);
        }
        #pragma unroll
        for (int c0 = 0; c0 < 512; c0 += 256) {
            int cc = c0 + tid, r = cc >> 3, q = cc & 7;
            int col = (q ^ (r & 7)) * 8;
            __builtin_amdgcn_global_load_lds(
                (cv_global*)(B + (size_t)(n0 + r) * 512 + k0 + col),
                (v_lds*)(Bsl + c0 * 8 + wave * 512), 16, 0, 0);
        }
        __syncthreads();
        #pragma unroll
        for (int j = 0; j < 2; ++j) {
            int kc = kq4 + j * 4;
            int rb0 = wn + fr, rb1 = wn + 16 + fr, ra = wm + fr;
            bf16x8 b0 = *(const bf16x8*)(Bsl + rb0 * 64 + (kc ^ (rb0 & 7)) * 8);
            bf16x8 b1 = *(const bf16x8*)(Bsl + rb1 * 64 + (kc ^ (rb1 & 7)) * 8);
            bf16x8 af = *(const bf16x8*)(Asl + ra * 64 + (kc ^ (ra & 7)) * 8);
            acc[0] = MFMA16(af, b0, acc[0], 0, 0, 0);
            acc[1] = MFMA16(af, b1, acc[1], 0, 0, 0);
        }
        __syncthreads();
    }
    const int crow = (lane >> 4) * 4, ccol = lane & 15;
    #pragma unroll
    for (int c = 0; c < 2; ++c) {
        int n = n0 + wn + c * 16 + ccol;
        float bj = bias[n];
        #pragma unroll
        for (int i = 0; i < 4; ++i) {
            size_t m = (size_t)(m0 + wm + crow + i);
            C[m * 512 + n] = fmaxf(acc[c][i] + bj, 0.f);
        }
    }
}

// ---------------------------------------------------------------------------
// out = LayerNorm(base + u) * g + be (+ optional bf16 copy).
// ---------------------------------------------------------------------------
__global__ __launch_bounds__(256)
void add_ln(const float* __restrict__ base, const float* __restrict__ u,
            const float* __restrict__ gam, const float* __restrict__ bet,
            float* __restrict__ out, unsigned short* __restrict__ outb) {
    const int row = blockIdx.x;
    const int tid = threadIdx.x, wave = tid >> 6, lane = tid & 63;
    const float* br = base + (size_t)row * EE;
    const float* ur = u + (size_t)row * EE;
    float t0 = br[tid] + ur[tid];
    float t1 = br[tid + 256] + ur[tid + 256];
    float s = t0 + t1, sq = t0 * t0 + t1 * t1;
    #pragma unroll
    for (int m = 32; m; m >>= 1) {
        s += __shfl_xor(s, m);
        sq += __shfl_xor(sq, m);
    }
    __shared__ float ssum[4], ssq[4];
    if (lane == 0) { ssum[wave] = s; ssq[wave] = sq; }
    __syncthreads();
    s = ssum[0] + ssum[1] + ssum[2] + ssum[3];
    sq = ssq[0] + ssq[1] + ssq[2] + ssq[3];
    float mean = s * (1.0f / EE);
    float var = sq * (1.0f / EE) - mean * mean;
    float inv = rsqrtf(var + LNEPS);
    float v0 = (t0 - mean) * inv * gam[tid] + bet[tid];
    float v1 = (t1 - mean) * inv * gam[tid + 256] + bet[tid + 256];
    float* orow = out + (size_t)row * EE;
    orow[tid] = v0;
    orow[tid + 256] = v1;
    if (outb) {
        unsigned short* obr = outb + (size_t)row * EE;
        obr[tid] = f2bf(v0);
        obr[tid + 256] = f2bf(v1);
    }
}

// ---------------------------------------------------------------------------
extern "C" void kernel_launch(void* const* d_in, const int* in_sizes, int n_in,
                              void* d_out, int out_size, void* d_ws,
                              size_t ws_size, hipStream_t stream) {
    const float* x    = (const float*)d_in[0];
    const float* Wqkv = (const float*)d_in[1];
    const float* bqkv = (const float*)d_in[2];
    const float* Wo   = (const float*)d_in[3];
    const float* bo   = (const float*)d_in[4];
    const float* W1   = (const float*)d_in[5];
    const float* b1   = (const float*)d_in[6];
    const float* W2   = (const float*)d_in[7];
    const float* b2   = (const float*)d_in[8];
    const float* g1   = (const float*)d_in[9];
    const float* be1  = (const float*)d_in[10];
    const float* g2   = (const float*)d_in[11];
    const float* be2  = (const float*)d_in[12];
    const float* d1W1 = (const float*)d_in[13];
    const float* d1b1 = (const float*)d_in[14];
    const float* d1W2 = (const float*)d_in[15];
    const float* d1b2 = (const float*)d_in[16];
    const float* d2W1 = (const float*)d_in[17];
    const float* d2b1 = (const float*)d_in[18];
    const float* d2W2 = (const float*)d_in[19];
    const float* d2b2 = (const float*)d_in[20];

    float* out      = (float*)d_out;
    float* out_main = out;
    float* x1_attn  = out + 1048576;
    float* x2_attn  = out + 1048576 + 131072;
    float* diff1    = out + 1048576 + 2 * 131072;
    float* diff2    = out + 1048576 + 3 * 131072;

    float* ws    = (float*)d_ws;
    float* u_buf = ws;                              // 2048*512
    float* h_buf = ws + 1048576;                    // 2048*512
    float* pws   = ws + 2097152;                    // 32*4*64*64
    float* b_eff = ws + 2621440;                    // 512
    unsigned short* Pl2 = (unsigned short*)(ws + 2621952);  // 2048*64 bf16
    unsigned short* bb  = (unsigned short*)(ws + 2687488);

    unsigned short* xb    = bb + XB_O;
    unsigned short* Wfull = bb + WFULL_O;
    unsigned short* W1cb  = bb + W1CB_O;
    unsigned short* W2b   = bb + W2B_O;
    unsigned short* qkvb  = bb + QKVB_O;
    unsigned short* x1o   = bb + X1O_O;
    unsigned short* hb    = bb + HB_O;
    unsigned short* Pb    = bb + PB_O;

    // 1: convert + Wc prep + b_eff + Gram L2-attention (2 blocks/batch)
    mega1<<<1540, 256, 0, stream>>>(x, Wqkv, Wo, W1, W2, d1W1, d2W1, b1, bo,
                                    bb, b_eff, x1_attn, Pl2);

    // 2: [qkv | P] = xb @ Wfull^T  +  x1 = Pl2 @ xb  (x1 -> x1o[:, :512])
    gemm_qkvp<<<dim3(36, 32), 256, 0, stream>>>(xb, Wfull, bqkv, qkvb, Pb,
                                                Pl2, x1o);

    // 3: attention; o -> x1o[:,512:], probs -> pws
    mha_attn<<<dim3(8, 32), 256, 0, stream>>>(qkvb, x1o, pws);

    // 4: u = relu([x1|o] @ [W1a|Wc]^T + b_eff)  +  pair MLPs
    w1pair<<<2560, 256, 0, stream>>>(x1o, W1cb, b_eff, u_buf, Pb, x1_attn, pws,
                                     d1b1, d1W2, d1b2, d2b1, d2W2, d2b2,
                                     x2_attn, diff1, diff2);

    // 5: h = LN(x + u) -> h_buf (f32) + hb (bf16)
    add_ln<<<2048, 256, 0, stream>>>(x, u_buf, g1, be1, h_buf, hb);

    // 6: u = relu(h @ W2^T + b2)
    gemm_w2<<<dim3(8, 64), 256, 0, stream>>>(hb, W2b, b2, u_buf);

    // 7: out = LN2(h + u)
    add_ln<<<2048, 256, 0, stream>>>(h_buf, u_buf, g2, be2, out_main, nullptr);
}